// Round 8
// baseline (1490.757 us; speedup 1.0000x reference)
//
#include <hip/hip_runtime.h>
#include <hip/hip_fp16.h>
#include <math.h>

// CSR keys (dst<<3 | src>>14) kept from round 7 (cheap, spreads fill atomics).
// NEW: the fp16 gather state is split into 2 feature slices of 32 (64 B rows,
// full cache lines). Slice = blockIdx&1 -> with round-robin block->XCD
// dispatch, each XCD gathers from only ONE 6.4 MB slice -> higher L2 hit.

#define WSH 14
#define KSH 3

// ---------------- init / histogram / norm ----------------

__global__ void zero_i32(int* __restrict__ p, int n) {
    int i = blockIdx.x * blockDim.x + threadIdx.x;
    if (i < n) p[i] = 0;
}

__global__ void hist_k(const int* __restrict__ src, const int* __restrict__ dst,
                       int E, int* __restrict__ counts) {
    int e = blockIdx.x * blockDim.x + threadIdx.x;
    if (e < E) {
        int key = (dst[e] << KSH) | (src[e] >> WSH);
        atomicAdd(&counts[key], 1);
    }
}

__global__ void dinv_k(const int* __restrict__ rowptr, float* __restrict__ dinv, int N) {
    int i = blockIdx.x * blockDim.x + threadIdx.x;
    if (i < N) {
        int deg = rowptr[(i + 1) << KSH] - rowptr[i << KSH];
        dinv[i] = rsqrtf((float)(deg + 1));  // +1 self-loop
    }
}

// zero dummy row N (2 slices x 16 half2) of the three gather buffers
__global__ void zero_dummy(__half2* __restrict__ b0, __half2* __restrict__ b1,
                           __half2* __restrict__ b2, int N) {
    int t = threadIdx.x;
    if (t >= 96) return;
    __half2* b = (t < 32) ? b0 : (t < 64) ? b1 : b2;
    int r = t & 31, s = r >> 4, h = r & 15;
    b[((size_t)s * (N + 1) + N) * 16 + h] = __floats2half2_rn(0.f, 0.f);
}

// ---------------- 3-pass exclusive scan over nk elems ----------------

__global__ void scan_pass1(const int* __restrict__ counts, int n, int* __restrict__ bsum) {
    __shared__ int s[256];
    int t = threadIdx.x;
    int base = blockIdx.x * 1024 + t * 4;
    int sum = 0;
    for (int j = 0; j < 4; ++j) { int i = base + j; if (i < n) sum += counts[i]; }
    s[t] = sum; __syncthreads();
    for (int off = 128; off > 0; off >>= 1) {
        if (t < off) s[t] += s[t + off];
        __syncthreads();
    }
    if (t == 0) bsum[blockIdx.x] = s[0];
}

__global__ void scan_pass2(const int* __restrict__ bsum, int nb, int* __restrict__ boff) {
    __shared__ int s[256];
    int t = threadIdx.x;
    int C = (nb + 255) / 256;
    int b0 = t * C;
    int loc[8]; int sum = 0;
    for (int i = 0; i < C; ++i) {
        int v = (b0 + i < nb) ? bsum[b0 + i] : 0;
        loc[i] = sum; sum += v;
    }
    s[t] = sum; __syncthreads();
    for (int off = 1; off < 256; off <<= 1) {
        int v = (t >= off) ? s[t - off] : 0;
        __syncthreads();
        s[t] += v;
        __syncthreads();
    }
    int excl = s[t] - sum;
    for (int i = 0; i < C; ++i)
        if (b0 + i < nb) boff[b0 + i] = excl + loc[i];
}

__global__ void scan_pass3(const int* __restrict__ counts, int n,
                           const int* __restrict__ boff, int* __restrict__ rowptr, int E) {
    __shared__ int s[256];
    int t = threadIdx.x;
    int base = blockIdx.x * 1024 + t * 4;
    int c[4]; int sum = 0;
    for (int j = 0; j < 4; ++j) { int i = base + j; c[j] = (i < n) ? counts[i] : 0; sum += c[j]; }
    s[t] = sum; __syncthreads();
    for (int off = 1; off < 256; off <<= 1) {
        int v = (t >= off) ? s[t - off] : 0;
        __syncthreads();
        s[t] += v;
        __syncthreads();
    }
    int excl = s[t] - sum + boff[blockIdx.x];
    for (int j = 0; j < 4; ++j) {
        int i = base + j;
        if (i < n) { rowptr[i] = excl; excl += c[j]; }
    }
    if (blockIdx.x == 0 && t == 0) rowptr[n] = E;
}

// ---------------- CSR fill: col index only (4B scatter) ----------------

__global__ void fill_k(const int* __restrict__ src, const int* __restrict__ dst, int E,
                       const int* __restrict__ rowptr,
                       int* __restrict__ cursor, int* __restrict__ col) {
    int e = blockIdx.x * blockDim.x + threadIdx.x;
    if (e >= E) return;
    int s = src[e], d = dst[e];
    int key = (d << KSH) | (s >> WSH);
    int pos = rowptr[key] + atomicAdd(&cursor[key], 1);
    col[pos] = s;
}

// ---------------- g0 = x @ W : LDS-tiled, 128 rows x 64 cols per block ----------------
// Emits fp32 g0 (teleport term) and the prescaled fp16 SLICED gather buffer:
// gh0[slice][(n)*16 + h] = dinv[n] * g0[n, 32*slice + 2h .. +1], slice = col>>5.

__global__ void __launch_bounds__(256) gemm_k(const float* __restrict__ x,
                                              const float* __restrict__ W,
                                              const float* __restrict__ dinv,
                                              float* __restrict__ g0,
                                              __half2* __restrict__ gh0, int N) {
    __shared__ float Ws[128 * 64];
    __shared__ float xs[128 * 133];
    int t = threadIdx.x;
    for (int i = t; i < 128 * 64; i += 256) Ws[i] = W[i];
    int n0 = blockIdx.x * 128;
    for (int f = t; f < 128 * 32; f += 256) {
        int r = f >> 5, c4 = f & 31;
        int n = n0 + r;
        float4 v = (n < N) ? ((const float4*)x)[(size_t)n * 32 + c4]
                           : make_float4(0.f, 0.f, 0.f, 0.f);
        float* dp = &xs[r * 133 + c4 * 4];
        dp[0] = v.x; dp[1] = v.y; dp[2] = v.z; dp[3] = v.w;
    }
    __syncthreads();
    int tr = t & 15, tc = t >> 4;
    int j0 = tr * 4, r0 = tc * 8;
    float acc[8][4] = {};
#pragma unroll 4
    for (int k = 0; k < 128; ++k) {
        float4 wv = *(const float4*)&Ws[k * 64 + j0];
#pragma unroll
        for (int i = 0; i < 8; ++i) {
            float xv = xs[(r0 + i) * 133 + k];
            acc[i][0] += xv * wv.x; acc[i][1] += xv * wv.y;
            acc[i][2] += xv * wv.z; acc[i][3] += xv * wv.w;
        }
    }
    int sl = j0 >> 5, h0 = (j0 & 31) >> 1;
#pragma unroll
    for (int i = 0; i < 8; ++i) {
        int n = n0 + r0 + i;
        if (n < N) {
            float4 v = make_float4(acc[i][0], acc[i][1], acc[i][2], acc[i][3]);
            *(float4*)&g0[(size_t)n * 64 + j0] = v;
            float dn = dinv[n];
            __half2* gp = &gh0[((size_t)sl * (N + 1) + n) * 16 + h0];
            gp[0] = __floats2half2_rn(v.x * dn, v.y * dn);
            gp[1] = __floats2half2_rn(v.z * dn, v.w * dn);
        }
    }
}

// ---------------- propagation (2 XCD-pinned feature slices) ----------------
// g_hat = dinv[n]*h[n], fp16, slice-rows of 32 features = 64 B (full line).
//   S = sum_e g_hat[src_e];  r = 0.9*dinv[d]*(S + g_hat[d]) + 0.1*g0[d]
// One wave per (dst row, slice). 16 lanes per edge -> 4 edges per gather
// instruction; edge cols broadcast via readlane + cndmask group-select.
// 16 edges (4 gathers) in flight; masked tail via zeroed dummy row N.

__global__ void __launch_bounds__(256) prop_k(const __half2* __restrict__ gin,
                                              const float* __restrict__ g0,
                                              __half2* __restrict__ gout,
                                              float* __restrict__ outf,
                                              const int* __restrict__ rowptr,
                                              const int* __restrict__ cols,
                                              const float* __restrict__ dinv,
                                              const float* __restrict__ bias,
                                              int N, int final_step) {
    int slice = blockIdx.x & 1;                  // pins slice to XCD parity
    int row = (blockIdx.x >> 1) * 4 + (threadIdx.x >> 6);
    if (row >= N) return;
    int lane = threadIdx.x & 63;
    int grp = lane >> 4, lf = lane & 15;         // 4 edge-groups x 16 half2 lanes

    const __half2* gs = gin + (size_t)slice * (N + 1) * 16;
    int beg = rowptr[row << KSH];
    int end = rowptr[(row + 1) << KSH];
    int deg = end - beg;

    // hoisted epilogue operands
    float di   = dinv[row];
    float2 gi  = __half22float2(gs[(size_t)row * 16 + lf]);
    float2 g0v = ((const float2*)g0)[(size_t)row * 32 + slice * 16 + lf];

    float ax = 0.f, ay = 0.f;

    for (int base = 0; base < deg; base += 64) {
        int m = deg - base; if (m > 64) m = 64;
        int idx = beg + base + (lane < m ? lane : 0);
        int ci = cols[idx];                      // 64 edge cols, one load
        int j = 0;
        for (; j + 15 < m; j += 16) {            // 16 edges, 4 gathers in flight
            float2 f[4];
#pragma unroll
            for (int u = 0; u < 4; ++u) {
                int e0 = j + 4 * u;
                int c0 = __builtin_amdgcn_readlane(ci, e0);
                int c1 = __builtin_amdgcn_readlane(ci, e0 + 1);
                int c2 = __builtin_amdgcn_readlane(ci, e0 + 2);
                int c3 = __builtin_amdgcn_readlane(ci, e0 + 3);
                int cl = (grp & 1) ? c1 : c0;
                int ch = (grp & 1) ? c3 : c2;
                int c  = (grp & 2) ? ch : cl;
                f[u] = __half22float2(gs[(size_t)c * 16 + lf]);
            }
#pragma unroll
            for (int u = 0; u < 4; ++u) { ax += f[u].x; ay += f[u].y; }
        }
        if (j < m) {                             // masked tail (<16 edges)
            float2 f[4];
#pragma unroll
            for (int u = 0; u < 4; ++u) {
                int e0 = j + 4 * u;
                int e  = e0 + grp;
                int c0 = __builtin_amdgcn_readlane(ci, e0 < 61 ? e0 : 61);
                int c1 = __builtin_amdgcn_readlane(ci, e0 + 1 < 62 ? e0 + 1 : 62);
                int c2 = __builtin_amdgcn_readlane(ci, e0 + 2 < 63 ? e0 + 2 : 63);
                int c3 = __builtin_amdgcn_readlane(ci, e0 + 3 < 63 ? e0 + 3 : 63);
                int cl = (grp & 1) ? c1 : c0;
                int ch = (grp & 1) ? c3 : c2;
                int c  = (grp & 2) ? ch : cl;
                if (e >= m) c = N;               // dummy zero row
                f[u] = __half22float2(gs[(size_t)c * 16 + lf]);
            }
#pragma unroll
            for (int u = 0; u < 4; ++u) { ax += f[u].x; ay += f[u].y; }
        }
    }

    // reduce the 4 edge-groups (butterfly over lane bits 4,5)
    ax += __shfl(ax, lane ^ 16, 64); ay += __shfl(ay, lane ^ 16, 64);
    ax += __shfl(ax, lane ^ 32, 64); ay += __shfl(ay, lane ^ 32, 64);

    if (grp == 0) {
        float rx = 0.9f * di * (ax + gi.x) + 0.1f * g0v.x;
        float ry = 0.9f * di * (ay + gi.y) + 0.1f * g0v.y;
        if (final_step) {
            float2 bv = ((const float2*)bias)[slice * 16 + lf];
            ((float2*)outf)[(size_t)row * 32 + slice * 16 + lf] =
                make_float2(rx + bv.x, ry + bv.y);
        } else {
            __half2* go = gout + (size_t)slice * (N + 1) * 16;
            go[(size_t)row * 16 + lf] = __floats2half2_rn(di * rx, di * ry);
        }
    }
}

// ---------------- launch ----------------

extern "C" void kernel_launch(void* const* d_in, const int* in_sizes, int n_in,
                              void* d_out, int out_size, void* d_ws, size_t ws_size,
                              hipStream_t stream) {
    const float* x  = (const float*)d_in[0];
    const int*   ei = (const int*)d_in[1];
    const float* W  = (const float*)d_in[2];
    const float* b  = (const float*)d_in[3];
    float* out = (float*)d_out;

    const int N = in_sizes[0] / 128;
    const int E = in_sizes[1] / 2;
    const int* src = ei;
    const int* dst = ei + E;
    const int nk = (N + 1) << KSH;

    char* w = (char*)d_ws;
    size_t off = 0;
    auto alloc = [&](size_t bytes) -> void* {
        void* p = w + off;
        off += (bytes + 255) & ~(size_t)255;
        return p;
    };
    const size_t buf_h2 = (size_t)(N + 1) * 32;            // 2 slices x 16 half2
    float*   g0     = (float*)  alloc((size_t)N * 64 * 4);
    __half2* gh0    = (__half2*)alloc(buf_h2 * 4);
    __half2* bufA   = (__half2*)alloc(buf_h2 * 4);
    __half2* bufB   = (__half2*)alloc(buf_h2 * 4);
    int*     cols   = (int*)    alloc((size_t)E * 4);
    int*     rowptr = (int*)    alloc((size_t)(nk + 1) * 4);
    int*     counts = (int*)    alloc((size_t)nk * 4);
    float*   dinvv  = (float*)  alloc((size_t)N * 4);
    const int nb = (nk + 1023) / 1024;
    int*     bsum   = (int*)    alloc((size_t)nb * 4);
    int*     boff   = (int*)    alloc((size_t)nb * 4);

    const int nblkN = (N + 255) / 256;
    const int nblkK = (nk + 255) / 256;
    const int nblkE = (E + 255) / 256;

    zero_i32<<<nblkK, 256, 0, stream>>>(counts, nk);
    hist_k<<<nblkE, 256, 0, stream>>>(src, dst, E, counts);
    zero_dummy<<<1, 96, 0, stream>>>(gh0, bufA, bufB, N);
    scan_pass1<<<nb, 256, 0, stream>>>(counts, nk, bsum);
    scan_pass2<<<1, 256, 0, stream>>>(bsum, nb, boff);
    scan_pass3<<<nb, 256, 0, stream>>>(counts, nk, boff, rowptr, E);
    dinv_k<<<nblkN, 256, 0, stream>>>(rowptr, dinvv, N);
    zero_i32<<<nblkK, 256, 0, stream>>>(counts, nk);
    fill_k<<<nblkE, 256, 0, stream>>>(src, dst, E, rowptr, counts, cols);

    gemm_k<<<(N + 127) / 128, 256, 0, stream>>>(x, W, dinvv, g0, gh0, N);

    // K = 10 APPNP steps; grid = 2 slices interleaved in blockIdx parity
    const int gridP = ((N + 3) / 4) * 2;
    const __half2* gin = gh0;
    __half2* pp[2] = {bufA, bufB};
    for (int k = 0; k < 10; ++k) {
        const bool fin = (k == 9);
        __half2* gout = pp[k & 1];
        prop_k<<<gridP, 256, 0, stream>>>(gin, g0, gout, out, rowptr, cols,
                                          dinvv, b, N, fin ? 1 : 0);
        gin = gout;
    }
}